// Round 1
// 482.103 us; speedup vs baseline: 1.0115x; 1.0115x over previous
//
#include <hip/hip_runtime.h>
#include <math.h>

// Problem constants (fixed by setup_inputs): x (B_T=512, N=197, C=768) fp32,
// T=16, B=32. Only the N=0 (cls) row of each (b,t) slab is transformed; the
// 196 patch rows pass through. Memory-bound: ~620 MB HBM traffic -> ~98.5 us
// at the 6.29 TB/s float4-copy ceiling. Measured metric also contains ~382 us
// of harness re-poison fills (2 x 191 us) that we cannot touch.

#define C_    768
#define N_    197
#define T_    16
#define HALF_ 384
#define SLAB  ((size_t)N_ * C_)        // floats per (b,t) slab = 151296
#define ROW4  37824u                   // SLAB / 4 (float4 per slab)
#define CLS4  192u                     // C_ / 4 (float4 in the cls row)
#define PBLK  147u                     // (ROW4 - CLS4) / 256: copy blocks/slab, exact
#define NSLAB 512u
#define COPY_BLOCKS (NSLAB * PBLK)     // 75264

typedef float f32x4 __attribute__((ext_vector_type(4)));

// Block-wide reduction of two values over 256 threads (4 waves of 64).
__device__ inline float2 block_reduce2(float a, float b) {
    __shared__ float sa[4], sb[4];
    #pragma unroll
    for (int off = 32; off; off >>= 1) {
        a += __shfl_down(a, off, 64);
        b += __shfl_down(b, off, 64);
    }
    int lane = threadIdx.x & 63, w = threadIdx.x >> 6;
    __syncthreads();                       // protect sa/sb from prior use
    if (lane == 0) { sa[w] = a; sb[w] = b; }
    __syncthreads();
    return make_float2(sa[0] + sa[1] + sa[2] + sa[3],
                       sb[0] + sb[1] + sb[2] + sb[3]);
}

// LN -> ReLU -> 2-wide FC -> tanh for one cls row held in registers v[3].
__device__ inline float2 compute_gates(const float* v, const float* ga,
                                       const float* be, const float* w0,
                                       const float* w1, float fb0, float fb1) {
    float s  = v[0] + v[1] + v[2];
    float ss = v[0]*v[0] + v[1]*v[1] + v[2]*v[2];
    float2 r = block_reduce2(s, ss);
    float mean = r.x * (1.f / (float)C_);
    float var  = r.y * (1.f / (float)C_) - mean * mean;
    float rstd = rsqrtf(var + 1e-5f);
    float d0 = 0.f, d1 = 0.f;
    #pragma unroll
    for (int i = 0; i < 3; i++) {
        float h = (v[i] - mean) * rstd * ga[i] + be[i];
        h = fmaxf(h, 0.f);
        d0 += h * w0[i];
        d1 += h * w1[i];
    }
    float2 d = block_reduce2(d0, d1);
    return make_float2(tanhf(d.x + fb0), tanhf(d.y + fb1));
}

__global__ __launch_bounds__(256) void gsm_kernel(
        const float* __restrict__ x, const float* __restrict__ gamma,
        const float* __restrict__ beta, const float* __restrict__ fw,
        const float* __restrict__ fb, float* __restrict__ out) {
    int tid = threadIdx.x;

    if (blockIdx.x < NSLAB) {
        // ---- cls path: one block per (b,t) row ----
        int bt = blockIdx.x;
        int t  = bt & (T_ - 1);
        const float* rowc = x + (size_t)bt * SLAB;
        const bool hasp = (t > 0), hasn = (t < T_ - 1);
        const float* rowp = rowc - SLAB;
        const float* rown = rowc + SLAB;

        float vc[3], vp[3], vn[3], ga[3], be[3], w0[3], w1[3];
        #pragma unroll
        for (int i = 0; i < 3; i++) {
            int c = tid + i * 256;
            vc[i] = rowc[c];
            vp[i] = hasp ? rowp[c] : 0.f;
            vn[i] = hasn ? rown[c] : 0.f;
            ga[i] = gamma[c];
            be[i] = beta[c];
            w0[i] = fw[c];
            w1[i] = fw[C_ + c];
        }
        float fb0 = fb[0], fb1 = fb[1];

        float2 gc = compute_gates(vc, ga, be, w0, w1, fb0, fb1);
        float2 gp = make_float2(0.f, 0.f), gn = make_float2(0.f, 0.f);
        if (hasp) gp = compute_gates(vp, ga, be, w0, w1, fb0, fb1); // block-uniform branch
        if (hasn) gn = compute_gates(vn, ga, be, w0, w1, fb0, fb1);

        float* orow = out + (size_t)bt * SLAB;
        #pragma unroll
        for (int i = 0; i < 3; i++) {
            int c = tid + i * 256;
            float o;
            if (c < HALF_) o = vc[i] * (1.f - gc.y) + gp.y * vp[i]; // new_g2
            else           o = vc[i] * (1.f - gc.x) + gn.x * vn[i]; // new_g1
            orow[c] = o;
        }
    } else {
        // ---- copy path: float4 pass-through of patch tokens ----
        // Exact-fit decomposition: 147 blocks x 256 float4-threads cover the
        // 37632 patch float4s of one slab. slab/chunk are blockIdx-uniform
        // (scalar-unit magic-mul); per-thread addr is base + tid. No per-thread
        // modulo, no bounds check, no divergence. Nontemporal: zero-reuse
        // 620 MB stream should not allocate in L2/L3.
        unsigned b = blockIdx.x - NSLAB;
        unsigned s = b / PBLK;             // slab index   (wave-uniform)
        unsigned k = b - s * PBLK;         // chunk in slab (wave-uniform)
        unsigned idx = s * ROW4 + CLS4 + k * 256u + (unsigned)tid;
        const f32x4* in4 = (const f32x4*)x;
        f32x4* out4 = (f32x4*)out;
        f32x4 v = __builtin_nontemporal_load(in4 + idx);
        __builtin_nontemporal_store(v, out4 + idx);
    }
}

extern "C" void kernel_launch(void* const* d_in, const int* in_sizes, int n_in,
                              void* d_out, int out_size, void* d_ws, size_t ws_size,
                              hipStream_t stream) {
    const float* x     = (const float*)d_in[0];
    const float* gamma = (const float*)d_in[1];
    const float* beta  = (const float*)d_in[2];
    const float* fw    = (const float*)d_in[3];
    const float* fb    = (const float*)d_in[4];
    // d_in[5] = num_frames (16), compile-time constant here.
    float* out = (float*)d_out;

    dim3 grid(NSLAB + COPY_BLOCKS);
    gsm_kernel<<<grid, 256, 0, stream>>>(x, gamma, beta, fw, fb, out);
}